// Round 28
// baseline (122.816 us; speedup 1.0000x reference)
//
#include <hip/hip_runtime.h>
#include <cstddef>

#define TPB 256

typedef short bf8v  __attribute__((ext_vector_type(8)));   // 8 bf16 bit-patterns
typedef float f32x4 __attribute__((ext_vector_type(4)));
typedef unsigned short u16;

#define PSZ 2048     // u16 per LDS plane [64][32] (rgemm staging)
#define PSZ2 4096    // u16 per LDS plane [64][64] (BK=64 staging)
#define LSTR 40      // stride for sgemm16 staging
#define BUF1 2560
#define CSTR 68      // f32 LDS epilogue-tile row stride
#define RTBUF 12288  // u16 per retiled buffer: A 2x[64][64] + B 2x[32][64]
#define XBUF 8192    // u16 per xmh buffer: A[128][32] + Br[64][32] + Bi[64][32]

static __device__ __forceinline__ u16 f2bf(float x) {
  unsigned int u = __float_as_uint(x);
  u = (u + 0x7FFFu + ((u >> 16) & 1u)) >> 16;   // RNE f32 -> bf16
  return (u16)u;
}
static __device__ __forceinline__ float bf2f(u16 x) {
  return __uint_as_float(((unsigned int)x) << 16);
}
static __device__ __forceinline__ float sigmoidf_(float x) {
  return 1.0f / (1.0f + __expf(-x));            // fast exp (v_exp_f32)
}
static __device__ __forceinline__ float spf_(float v) {   // fast softplus
  return (v > 15.0f) ? v : __logf(1.0f + __expf(v));
}
static __device__ __forceinline__ bf8v neg8(bf8v a) {
  #pragma unroll
  for (int i = 0; i < 8; ++i) a[i] ^= (short)0x8000;
  return a;
}
static __device__ __forceinline__ void pack8(const float4& x, const float4& y,
                                             u16* dst) {
  unsigned int* d = (unsigned int*)dst;
  d[0] = ((unsigned)f2bf(x.y) << 16) | f2bf(x.x);
  d[1] = ((unsigned)f2bf(x.w) << 16) | f2bf(x.z);
  d[2] = ((unsigned)f2bf(y.y) << 16) | f2bf(y.x);
  d[3] = ((unsigned)f2bf(y.w) << 16) | f2bf(y.z);
}
static __device__ __forceinline__ uint2 packbf4(float a, float b, float c, float d) {
  uint2 r;
  r.x = ((unsigned)f2bf(b) << 16) | f2bf(a);
  r.y = ((unsigned)f2bf(d) << 16) | f2bf(c);
  return r;
}
// async global->LDS, 16B per lane; LDS dest is wave-uniform base + lane*16
static __device__ __forceinline__ void gload16(const u16* g, u16* l) {
  __builtin_amdgcn_global_load_lds((const __attribute__((address_space(1))) void*)g,
                                   (__attribute__((address_space(3))) void*)l,
                                   16, 0, 0);
}
// BK=32 fragment read with k-chunk XOR swizzle (rgemm/xmh path)
static __device__ __forceinline__ bf8v fragld(const u16* plane, int r, int kq) {
  int kb = (kq << 4) ^ (((r >> 1) & 3) << 4);
  return *(const bf8v*)(plane + r * 32 + (kb >> 1));
}
// BK=64 fragment read: global chunk (s*4+kq) at row r lives at chunk^(r&7)
static __device__ __forceinline__ bf8v fragld2(const u16* plane, int r, int kq, int s) {
  int ch = ((s << 2) + kq) ^ (r & 7);
  return *(const bf8v*)(plane + r * 64 + (ch << 3));
}
// XCD-aware bijective block swizzle (T % 8 == 0)
static __device__ __forceinline__ int swz8(int flat, int T) {
  return (flat & 7) * (T >> 3) + (flat >> 3);
}

#define WAITV(n) asm volatile("s_waitcnt vmcnt(" #n ")" ::: "memory")

// ---------------------------------------------------------------------------
// A = (v - v^T)re + i(v + v^T)im ; N = I - A   -> bf16 planes
// ---------------------------------------------------------------------------
__global__ __launch_bounds__(TPB) void build_a_k(
    const float* __restrict__ vre, const float* __restrict__ vim,
    u16* __restrict__ Ar, u16* __restrict__ Ai,
    u16* __restrict__ Nr, u16* __restrict__ Ni)
{
  int idx = blockIdx.x * TPB + threadIdx.x;
  int i = idx >> 10, j = idx & 1023;
  float ar = vre[idx] - vre[j * 1024 + i];
  float ai = vim[idx] + vim[j * 1024 + i];
  float dg = (i == j) ? 1.0f : 0.0f;
  Ar[idx] = f2bf(ar);       Ai[idx] = f2bf(ai);
  Nr[idx] = f2bf(dg - ar);  Ni[idx] = f2bf(-ai);
}

// ---------------------------------------------------------------------------
// complex-NT, BK=64.  4-wave 64x64 (pair) and 4-wave 64x32 retile (a2/vmt).
// ---------------------------------------------------------------------------
#define CG_VARS                                                              \
  int lane = tid & 63;                                                       \
  int wr = (tid >> 7) & 1, wc = (tid >> 6) & 1;                              \
  int lr8_ = ((tid & 63) >> 3) + ((tid >> 6) << 4);                          \
  int ks2_ = (((lane & 7) ^ (lane >> 3)) << 3);                              \
  u16* Lw_ = lds + ((tid >> 6) << 10);                                       \
  f32x4 accR[2][2] = {};                                                     \
  f32x4 accI[2][2] = {};

#define CG_STAGE(buf, k0, PAr, PAi, PBr, PBi)                                \
  { u16* Lb = Lw_ + (buf) * (4 * PSZ2);                                      \
    gload16((PAr) + (size_t)(bm + lr8_) * 1024 + (k0) + ks2_,     Lb + 0 * PSZ2);       \
    gload16((PAr) + (size_t)(bm + lr8_ + 8) * 1024 + (k0) + ks2_, Lb + 0 * PSZ2 + 512); \
    gload16((PAi) + (size_t)(bm + lr8_) * 1024 + (k0) + ks2_,     Lb + 1 * PSZ2);       \
    gload16((PAi) + (size_t)(bm + lr8_ + 8) * 1024 + (k0) + ks2_, Lb + 1 * PSZ2 + 512); \
    gload16((PBr) + (size_t)(bn + lr8_) * 1024 + (k0) + ks2_,     Lb + 2 * PSZ2);       \
    gload16((PBr) + (size_t)(bn + lr8_ + 8) * 1024 + (k0) + ks2_, Lb + 2 * PSZ2 + 512); \
    gload16((PBi) + (size_t)(bn + lr8_) * 1024 + (k0) + ks2_,     Lb + 3 * PSZ2);       \
    gload16((PBi) + (size_t)(bn + lr8_ + 8) * 1024 + (k0) + ks2_, Lb + 3 * PSZ2 + 512); }

#define CG_FRAGS(buf, s)                                                     \
  const u16* L = lds + (buf) * (4 * PSZ2);                                   \
  int rA = wr * 32 + (lane & 15);                                            \
  int rB = wc * 32 + (lane & 15);                                            \
  int kq = lane >> 4;                                                        \
  bf8v ar[2], ai[2], br[2], bi[2];                                           \
  ar[0] = fragld2(L + 0 * PSZ2, rA, kq, s);  ar[1] = fragld2(L + 0 * PSZ2, rA + 16, kq, s); \
  ai[0] = fragld2(L + 1 * PSZ2, rA, kq, s);  ai[1] = fragld2(L + 1 * PSZ2, rA + 16, kq, s); \
  br[0] = fragld2(L + 2 * PSZ2, rB, kq, s);  br[1] = fragld2(L + 2 * PSZ2, rB + 16, kq, s); \
  bi[0] = fragld2(L + 3 * PSZ2, rB, kq, s);  bi[1] = fragld2(L + 3 * PSZ2, rB + 16, kq, s);

#define CG_MFMA_BNEG1                                                        \
  { bf8v nbi[2] = { neg8(bi[0]), neg8(bi[1]) };                              \
    _Pragma("unroll")                                                        \
    for (int mf = 0; mf < 2; ++mf)                                           \
      _Pragma("unroll")                                                      \
      for (int nf = 0; nf < 2; ++nf) {                                       \
        accR[mf][nf] = __builtin_amdgcn_mfma_f32_16x16x32_bf16(ar[mf], br[nf],  accR[mf][nf], 0, 0, 0); \
        accR[mf][nf] = __builtin_amdgcn_mfma_f32_16x16x32_bf16(ai[mf], bi[nf],  accR[mf][nf], 0, 0, 0); \
        accI[mf][nf] = __builtin_amdgcn_mfma_f32_16x16x32_bf16(ar[mf], nbi[nf], accI[mf][nf], 0, 0, 0); \
        accI[mf][nf] = __builtin_amdgcn_mfma_f32_16x16x32_bf16(ai[mf], br[nf],  accI[mf][nf], 0, 0, 0); \
      } }

#define CG_PIPELINE(MFMA_OP, PAr, PAi, PBr, PBi)                             \
  CG_STAGE(0, 0, PAr, PAi, PBr, PBi);                                        \
  _Pragma("unroll 1")                                                        \
  for (int t = 0; t < 16; ++t) {                                             \
    int bufc = t & 1;                                                        \
    if (t + 1 < 16) { CG_STAGE(bufc ^ 1, (t + 1) * 64, PAr, PAi, PBr, PBi);  \
                      WAITV(8); }                                            \
    else            { WAITV(0); }                                            \
    __builtin_amdgcn_sched_barrier(0);                                       \
    __builtin_amdgcn_s_barrier();                                            \
    __builtin_amdgcn_s_setprio(1);                                           \
    { CG_FRAGS(bufc, 0) MFMA_OP }                                            \
    { CG_FRAGS(bufc, 1) MFMA_OP }                                            \
    __builtin_amdgcn_s_setprio(0);                                           \
    __builtin_amdgcn_sched_barrier(0);                                       \
    __builtin_amdgcn_s_barrier();                                            \
  }

// ---- 64x32 retile, 4 waves (TPB): wave = wr (m-half) x wc (n-half of 32) --
// LDS buffer: Ar [64][64] @0, Ai @4096, Br [32][64] @8192, Bi @10240 (u16)
#define CGRT_VARS                                                            \
  int lane = tid & 63;                                                       \
  int wv = tid >> 6;                                                         \
  int wr = wv >> 1, wc = wv & 1;                                             \
  int ln8 = lane >> 3;                                                       \
  int ks2_ = (((lane & 7) ^ ln8) << 3);                                      \
  f32x4 accR[2] = {};                                                        \
  f32x4 accI[2] = {};

#define CGRT_STAGE(buf, k0, PAr, PAi, PBr, PBi)                              \
  { u16* Lb = lds + (buf) * RTBUF;                                           \
    _Pragma("unroll")                                                        \
    for (int j = 0; j < 6; ++j) {                                            \
      int idx = wv * 6 + j;                                                  \
      const u16* src; int row; int doff;                                     \
      if (idx < 16) {                                                        \
        int pl = idx >> 3, gr = idx & 7;                                     \
        src = pl ? (PAi) : (PAr);                                            \
        row = bm + gr * 8 + ln8;                                             \
        doff = pl * 4096 + gr * 512;                                         \
      } else {                                                               \
        int i2 = idx - 16;                                                   \
        int pl = i2 >> 2, gr = i2 & 3;                                       \
        src = pl ? (PBi) : (PBr);                                            \
        row = bn + gr * 8 + ln8;                                             \
        doff = 8192 + pl * 2048 + gr * 512;                                  \
      }                                                                      \
      gload16(src + (size_t)row * 1024 + (k0) + ks2_, Lb + doff);            \
    } }

#define CGRT_FRAGS(buf, s)                                                   \
  const u16* L = lds + (buf) * RTBUF;                                        \
  int rA = wr * 32 + (lane & 15);                                            \
  int rB = wc * 16 + (lane & 15);                                            \
  int kq = lane >> 4;                                                        \
  bf8v ar[2], ai[2], br1, bi1;                                               \
  ar[0] = fragld2(L, rA, kq, s);          ar[1] = fragld2(L, rA + 16, kq, s);          \
  ai[0] = fragld2(L + 4096, rA, kq, s);   ai[1] = fragld2(L + 4096, rA + 16, kq, s);   \
  br1 = fragld2(L + 8192, rB, kq, s);                                        \
  bi1 = fragld2(L + 10240, rB, kq, s);

#define CGRT_MFMA_BNEG0                                                      \
  { bf8v nbr = neg8(br1);                                                    \
    bf8v nbi = neg8(bi1);                                                    \
    _Pragma("unroll")                                                        \
    for (int mf = 0; mf < 2; ++mf) {                                         \
      accR[mf] = __builtin_amdgcn_mfma_f32_16x16x32_bf16(ar[mf], nbr, accR[mf], 0, 0, 0); \
      accR[mf] = __builtin_amdgcn_mfma_f32_16x16x32_bf16(ai[mf], nbi, accR[mf], 0, 0, 0); \
      accI[mf] = __builtin_amdgcn_mfma_f32_16x16x32_bf16(ar[mf], bi1, accI[mf], 0, 0, 0); \
      accI[mf] = __builtin_amdgcn_mfma_f32_16x16x32_bf16(ai[mf], nbr, accI[mf], 0, 0, 0); \
    } }

#define CGRT_MFMA_BNEG1                                                      \
  { bf8v nbi = neg8(bi1);                                                    \
    _Pragma("unroll")                                                        \
    for (int mf = 0; mf < 2; ++mf) {                                         \
      accR[mf] = __builtin_amdgcn_mfma_f32_16x16x32_bf16(ar[mf], br1, accR[mf], 0, 0, 0); \
      accR[mf] = __builtin_amdgcn_mfma_f32_16x16x32_bf16(ai[mf], bi1, accR[mf], 0, 0, 0); \
      accI[mf] = __builtin_amdgcn_mfma_f32_16x16x32_bf16(ar[mf], nbi, accI[mf], 0, 0, 0); \
      accI[mf] = __builtin_amdgcn_mfma_f32_16x16x32_bf16(ai[mf], br1, accI[mf], 0, 0, 0); \
    } }

#define CGRT_PIPELINE(MFMA_OP, PAr, PAi, PBr, PBi)                           \
  CGRT_STAGE(0, 0, PAr, PAi, PBr, PBi);                                      \
  _Pragma("unroll 1")                                                        \
  for (int t = 0; t < 16; ++t) {                                             \
    int bufc = t & 1;                                                        \
    if (t + 1 < 16) { CGRT_STAGE(bufc ^ 1, (t + 1) * 64, PAr, PAi, PBr, PBi);\
                      WAITV(6); }                                            \
    else            { WAITV(0); }                                            \
    __builtin_amdgcn_sched_barrier(0);                                       \
    __builtin_amdgcn_s_barrier();                                            \
    __builtin_amdgcn_s_setprio(1);                                           \
    { CGRT_FRAGS(bufc, 0) MFMA_OP }                                          \
    { CGRT_FRAGS(bufc, 1) MFMA_OP }                                          \
    __builtin_amdgcn_s_setprio(0);                                           \
    __builtin_amdgcn_sched_barrier(0);                                       \
    __builtin_amdgcn_s_barrier();                                            \
  }

// ---------------------------------------------------------------------------
// d2: bx<512: A2=A@A 64x32 retile | [512,2816): converts | [2816,2820): prep
//     [2820,3076): sgemm16 Wi
// ---------------------------------------------------------------------------
__global__ __launch_bounds__(TPB) void d2_k(
    const u16* __restrict__ Apr, const u16* __restrict__ Api,
    u16* __restrict__ A2r, u16* __restrict__ A2i,
    const float* __restrict__ X, const float* __restrict__ Wu1,
    const float* __restrict__ Wu2,
    const float* __restrict__ ld, const float* __restrict__ lf,
    const float* __restrict__ law_re, const float* __restrict__ law_im,
    const float* __restrict__ dt, const float* __restrict__ base_noise,
    u16* __restrict__ Xb, u16* __restrict__ Wu1b, u16* __restrict__ Wu2b,
    float* __restrict__ od_re, float* __restrict__ od_im,
    float* __restrict__ of_re, float* __restrict__ of_im,
    float* __restrict__ bvar,
    const float* __restrict__ xg_re, const float* __restrict__ xg_im,
    const float* __restrict__ Wi, float* __restrict__ PpI)
{
  __shared__ __align__(16) u16 lds[2 * RTBUF];          // 48KB
  int tid = threadIdx.x;
  int bx = blockIdx.x;
  if (bx < 512) {
    int flat = swz8(bx, 512);
    int bm = (flat >> 5) * 64, bn = (flat & 31) * 32;
    CGRT_VARS
    CGRT_PIPELINE(CGRT_MFMA_BNEG0, Apr, Api, Apr, Api)
    #pragma unroll
    for (int mf = 0; mf < 2; ++mf) {
      int col = bn + wc * 16 + (lane & 15);
      #pragma unroll
      for (int r = 0; r < 4; ++r) {
        int rowg = bm + wr * 32 + mf * 16 + (lane >> 4) * 4 + r;
        size_t o = (size_t)rowg * 1024 + col;
        A2r[o] = f2bf(accR[mf][r]);
        A2i[o] = f2bf(accI[mf][r]);
      }
    }
  } else if (bx < 2816) {
    int e = ((bx - 512) * TPB + tid) << 3;
    const float* src;
    u16* dst;
    if (e < 4194304)       { src = X + e;               dst = Xb + e; }
    else if (e < 4456448)  { src = Wu1 + (e - 4194304); dst = Wu1b + (e - 4194304); }
    else                   { src = Wu2 + (e - 4456448); dst = Wu2b + (e - 4456448); }
    float4 a = *(const float4*)src;
    float4 b = *(const float4*)(src + 4);
    u16 tmp[8];
    pack8(a, b, tmp);
    *(bf8v*)dst = *(bf8v*)tmp;
  } else if (bx < 2820) {
    int d = (bx - 2816) * TPB + tid;                    // 0..1023
    float dtr = dt[0];                                  // DT_REF = 1.0
    float lre = tanhf(-expf(ld[d]) + law_re[d]) * 0.3f;
    float lim = lf[d] + law_im[d];
    float er = expf(lre * dtr);
    float sn, cs;
    sincosf(lim * dtr, &sn, &cs);
    float odr = er * cs, odi = er * sn;
    od_re[d] = odr;  od_im[d] = odi;
    float numr = odr - 1.0f, numi = odi;
    float denr = lre + 1e-8f, deni = lim;
    float inv = 1.0f / (denr * denr + deni * deni);
    of_re[d] = (numr * denr + numi * deni) * inv;
    of_im[d] = (numi * denr - numr * deni) * inv;
    float bn2 = base_noise[0];
    float bv = bn2 * bn2 * expm1f(2.0f * lre * dtr) / (2.0f * lre + 1e-8f);
    bvar[d] = fmaxf(bv, 0.0f);
  } else {
    // sgemm16 Wi: M=16 split-K partials
    int id = bx - 2820;
    int c0 = (id & 31) * 64;
    int kbase = (id >> 5) * 256;
    int lane = tid & 63;
    int w = tid >> 6;
    int row = tid >> 2, kq = (tid & 3) << 3;

    f32x4 acc = {};
    float4 pb0, pb1;
    u16* sl = lds;

    auto gload = [&](int k0) {
      const float* p = Wi + (size_t)(c0 + row) * 2048 + k0 + kq;
      pb0 = *(const float4*)p; pb1 = *(const float4*)(p + 4);
    };
    auto stolds = [&](int buf) {
      pack8(pb0, pb1, sl + buf * BUF1 + row * LSTR + kq);
    };
    auto compute = [&](int buf, int k0) {
      int ar = lane & 15;
      int ko = (lane >> 4) * 8;
      const float* ap = (k0 < 1024) ? (xg_re + (size_t)ar * 1024 + k0 + ko)
                                    : (xg_im + (size_t)ar * 1024 + k0 + ko - 1024);
      float4 a0 = *(const float4*)ap, a1 = *(const float4*)(ap + 4);
      u16 abuf[8];
      pack8(a0, a1, abuf);
      bf8v af = *(bf8v*)abuf;
      bf8v bfr = *(const bf8v*)(sl + buf * BUF1 + (w * 16 + (lane & 15)) * LSTR + ko);
      acc = __builtin_amdgcn_mfma_f32_16x16x32_bf16(af, bfr, acc, 0, 0, 0);
    };

    gload(kbase); stolds(0); __syncthreads();
    int cur = 0;
    for (int t = 0; t < 8; ++t) {
      int k0 = kbase + t * 32;
      if (t < 7) gload(k0 + 32);
      compute(cur, k0);
      if (t < 7) stolds(cur ^ 1);
      __syncthreads();
      cur ^= 1;
    }
    int c = c0 + w * 16 + (lane & 15);
    #pragma unroll
    for (int r = 0; r < 4; ++r) {
      int rr = (lane >> 4) * 4 + r;
      PpI[((size_t)(id >> 5) * 16 + rr) * 2048 + c] = acc[r];
    }
  }
}

// ---------------------------------------------------------------------------
// d3: bx<512: batched pair (z=0: A4=A2@A2 ; z=1: T1=N@A2+N)
//     [512,576): fused red16(Wi) + flux -> FNr/FNi/out1
// ---------------------------------------------------------------------------
__global__ __launch_bounds__(TPB) void d3_k(
    const u16* __restrict__ A2r, const u16* __restrict__ A2i,
    const u16* __restrict__ Nr2, const u16* __restrict__ Ni2,
    u16* __restrict__ A4r, u16* __restrict__ A4i,
    u16* __restrict__ T1r, u16* __restrict__ T1i,
    const float* __restrict__ PpI, const float* __restrict__ bi,
    const float* __restrict__ flux_re, const float* __restrict__ flux_im,
    const float* __restrict__ decay_re, const float* __restrict__ decay_im,
    float* __restrict__ FNr, float* __restrict__ FNi,
    float* __restrict__ out1)
{
  __shared__ __align__(16) u16 lds[2 * 4 * PSZ2];       // 64KB
  int tid = threadIdx.x;
  int bx = blockIdx.x;
  if (bx < 512) {
    int flat = swz8(bx, 512);
    int z = flat >> 8;
    int t8 = flat & 255;
    int bm = (t8 >> 4) * 64, bn = (t8 & 15) * 64;
    const u16* Apr = z ? Nr2 : A2r;
    const u16* Api = z ? Ni2 : A2i;
    u16* Cr16 = z ? T1r : A4r;
    u16* Ci16 = z ? T1i : A4i;
    CG_VARS
    CG_PIPELINE(CG_MFMA_BNEG1, Apr, Api, A2r, A2i)
    #pragma unroll
    for (int mf = 0; mf < 2; ++mf)
      #pragma unroll
      for (int nf = 0; nf < 2; ++nf) {
        int col = bn + wc * 32 + nf * 16 + (lane & 15);
        #pragma unroll
        for (int r = 0; r < 4; ++r) {
          int rowg = bm + wr * 32 + mf * 16 + (lane >> 4) * 4 + r;
          size_t o = (size_t)rowg * 1024 + col;
          float vr = accR[mf][nf][r], vi = accI[mf][nf][r];
          if (z) { vr += bf2f(Nr2[o]); vi += bf2f(Ni2[o]); }   // +N
          Cr16[o] = f2bf(vr);
          Ci16[o] = f2bf(vi);
        }
      }
  } else {
    int idx = (bx - 512) * TPB + tid;   // 16 * 1024
    int b = idx >> 10, d = idx & 1023;
    float ur = bi[d];
    float ui = bi[1024 + d];
    #pragma unroll
    for (int s = 0; s < 8; ++s) {
      ur += PpI[(size_t)s * 32768 + b * 2048 + d];
      ui += PpI[(size_t)s * 32768 + b * 2048 + 1024 + d];
    }
    float fdr = sigmoidf_(decay_re[d]);
    float fdi = decay_im[d];
    float fr = flux_re[idx], fi = flux_im[idx];
    float nr = fr * fdr - fi * fdi + ur;
    float ni = fr * fdi + fi * fdr + ui;
    FNr[idx] = nr;  FNi[idx] = ni;
    out1[idx] = nr;                                // f32, real part only
  }
}

// ---------------------------------------------------------------------------
// d4: bx<512: V = 2*(T1@A4)+2*T1-I fused Mt build (64x32 retile)
//     [512,896): sgemm16 Wo+Wg split-K partials (filler under vmt stalls)
// ---------------------------------------------------------------------------
__global__ __launch_bounds__(TPB) void d4_k(
    const u16* __restrict__ T1r, const u16* __restrict__ T1i,
    const u16* __restrict__ A4r, const u16* __restrict__ A4i,
    const float* __restrict__ log_sigma, const float* __restrict__ dft_weight,
    u16* __restrict__ Mtr, u16* __restrict__ Mti,
    const float* __restrict__ FNr, const float* __restrict__ FNi,
    const float* __restrict__ Wo, const float* __restrict__ Wg,
    float* __restrict__ PpO, float* __restrict__ PpG)
{
  __shared__ __align__(16) u16 lds[2 * RTBUF];          // 48KB
  int tid = threadIdx.x;
  int bx = blockIdx.x;
  if (bx < 512) {
    int flat = swz8(bx, 512);
    int bm = (flat >> 5) * 64, bn = (flat & 31) * 32;   // bm=k-range, bn=d-range
    CGRT_VARS
    CGRT_PIPELINE(CGRT_MFMA_BNEG1, T1r, T1i, A4r, A4i)

    // fused Mt epilogue: compute in (k,d) position, transpose via LDS u16 tiles
    u16* mtLr = lds;              // [32][72] u16
    u16* mtLi = lds + 2304;
    __syncthreads();
    {
      float alpha = sigmoidf_(dft_weight[0]);
      const float isq = 0.03125f * alpha;
      #pragma unroll
      for (int mf = 0; mf < 2; ++mf) {
        int dl = wc * 16 + (lane & 15);               // local d (0..31)
        int dgl = bn + dl;                            // global d
        float w1 = expf(log_sigma[dgl]) * (1.0f - alpha);
        #pragma unroll
        for (int r = 0; r < 4; ++r) {
          int kl = wr * 32 + mf * 16 + (lane >> 4) * 4 + r;   // local k (0..63)
          int kgl = bm + kl;                                  // global k
          size_t o = (size_t)kgl * 1024 + dgl;
          float dg = (kgl == dgl) ? 1.0f : 0.0f;
          float vr = 2.0f * accR[mf][r] + 2.0f * bf2f(T1r[o]) - dg;
          float vi = 2.0f * accI[mf][r] + 2.0f * bf2f(T1i[o]);
          int mm = (kgl * dgl) & 1023;
          float ang = -6.283185307179586f * (float)mm * (1.0f / 1024.0f);
          float sn, cs;
          sincosf(ang, &sn, &cs);
          mtLr[dl * 72 + kl] = f2bf(vr * w1 + cs * isq);
          mtLi[dl * 72 + kl] = f2bf(vi * w1 + sn * isq);
        }
      }
    }
    __syncthreads();
    {
      int dl = tid >> 3, kl0 = (tid & 7) * 8;
      size_t o = (size_t)(bn + dl) * 1024 + bm + kl0;
      *(uint4*)(Mtr + o) = *(uint4*)(mtLr + dl * 72 + kl0);
      *(uint4*)(Mti + o) = *(uint4*)(mtLi + dl * 72 + kl0);
    }
  } else {
    // sgemm16 Wo+Wg: id in [0,384): c-block = id%48, k-chunk = id/48
    int id = bx - 512;
    int cb = id % 48;
    int ky = id / 48;
    const float* Bw = (cb < 32) ? Wo : Wg;
    float* Pp = (cb < 32) ? PpO : PpG;
    int N = (cb < 32) ? 2048 : 1024;
    int c0 = ((cb < 32) ? cb : (cb - 32)) * 64;
    int kbase = ky * 256;
    int lane = tid & 63;
    int w = tid >> 6;
    int row = tid >> 2, kq = (tid & 3) << 3;

    f32x4 acc = {};
    float4 pb0, pb1;
    u16* sl = lds;

    auto gload = [&](int k0) {
      const float* p = Bw + (size_t)(c0 + row) * 2048 + k0 + kq;
      pb0 = *(const float4*)p; pb1 = *(const float4*)(p + 4);
    };
    auto stolds = [&](int buf) {
      pack8(pb0, pb1, sl + buf * BUF1 + row * LSTR + kq);
    };
    auto compute = [&](int buf, int k0) {
      int ar = lane & 15;
      int ko = (lane >> 4) * 8;
      const float* ap = (k0 < 1024) ? (FNr + (size_t)ar * 1024 + k0 + ko)
                                    : (FNi + (size_t)ar * 1024 + k0 + ko - 1024);
      float4 a0 = *(const float4*)ap, a1 = *(const float4*)(ap + 4);
      u16 abuf[8];
      pack8(a0, a1, abuf);
      bf8v af = *(bf8v*)abuf;
      bf8v bfr = *(const bf8v*)(sl + buf * BUF1 + (w * 16 + (lane & 15)) * LSTR + ko);
      acc = __builtin_amdgcn_mfma_f32_16x16x32_bf16(af, bfr, acc, 0, 0, 0);
    };

    gload(kbase); stolds(0); __syncthreads();
    int cur = 0;
    for (int t = 0; t < 8; ++t) {
      int k0 = kbase + t * 32;
      if (t < 7) gload(k0 + 32);
      compute(cur, k0);
      if (t < 7) stolds(cur ^ 1);
      __syncthreads();
      cur ^= 1;
    }
    int c = c0 + w * 16 + (lane & 15);
    #pragma unroll
    for (int r = 0; r < 4; ++r) {
      int rr = (lane >> 4) * 4 + r;
      Pp[((size_t)ky * 16 + rr) * N + c] = acc[r];
    }
  }
}

// ---------------------------------------------------------------------------
// x_tilde = Xb @ M + h_next epilogue -> Hrb bf16.  Fused Wo/Wg reduce.
// 128x64 tile, 4 waves (64x32 acc each). BK=32, 3-buffer counted-vmcnt
// (rgemm-style: 2-phase-ahead prefetch, 48KB LDS -> 3 blocks/CU).
// ---------------------------------------------------------------------------
__global__ __launch_bounds__(TPB) void xmh_nt_k(
    const u16* __restrict__ Xb,
    const u16* __restrict__ Mtr, const u16* __restrict__ Mti,
    const float* __restrict__ PpO, const float* __restrict__ PpG,
    const float* __restrict__ bo, const float* __restrict__ bg,
    const float* __restrict__ od_re, const float* __restrict__ od_im,
    const float* __restrict__ of_re, const float* __restrict__ of_im,
    const float* __restrict__ hp_re, const float* __restrict__ hp_im,
    u16* __restrict__ Hrb)
{
  __shared__ __align__(16) u16 lds[3 * XBUF];         // 48KB
  int flat = swz8(blockIdx.x, 512);
  int bm = (flat >> 4) * 128, bn = (flat & 15) * 64;
  int tid = threadIdx.x;
  int lane = tid & 63;
  int wv = tid >> 6;
  int wr = wv >> 1, wc = wv & 1;
  int lr4 = lane >> 2;                                // row within 16-row group
  int ks_ = (((lane & 3) ^ ((lane >> 3) & 3)) << 3);  // BK=32 staging swizzle

  f32x4 accR[4][2] = {};
  f32x4 accI[4][2] = {};

  // buffer layout (u16): A[128][32] @0, Br[64][32] @4096, Bi[64][32] @6144
#define XM_STAGE(buf, k0)                                                    \
  { u16* Lb = lds + (buf) * XBUF;                                            \
    _Pragma("unroll")                                                        \
    for (int j = 0; j < 4; ++j) {                                            \
      int idx = wv * 4 + j;                                                  \
      const u16* src; int row; int doff;                                     \
      if (idx < 8)       { src = Xb;  row = bm + idx * 16 + lr4;                    \
                           doff = idx * 512; }                               \
      else if (idx < 12) { src = Mtr; row = bn + (idx - 8) * 16 + lr4;              \
                           doff = 4096 + (idx - 8) * 512; }                  \
      else               { src = Mti; row = bn + (idx - 12) * 16 + lr4;             \
                           doff = 6144 + (idx - 12) * 512; }                 \
      gload16(src + (size_t)row * 1024 + (k0) + ks_, Lb + doff);             \
    } }
#define XM_COMPUTE(buf)                                                      \
  { const u16* L = lds + (buf) * XBUF;                                       \
    int kq = lane >> 4;                                                      \
    bf8v a[4], br[2], bi[2];                                                 \
    _Pragma("unroll")                                                        \
    for (int mf = 0; mf < 4; ++mf)                                           \
      a[mf] = fragld(L, wr * 64 + mf * 16 + (lane & 15), kq);                \
    _Pragma("unroll")                                                        \
    for (int nf = 0; nf < 2; ++nf) {                                         \
      br[nf] = fragld(L + 4096, wc * 32 + nf * 16 + (lane & 15), kq);        \
      bi[nf] = fragld(L + 6144, wc * 32 + nf * 16 + (lane & 15), kq);        \
    }                                                                        \
    _Pragma("unroll")                                                        \
    for (int mf = 0; mf < 4; ++mf)                                           \
      _Pragma("unroll")                                                      \
      for (int nf = 0; nf < 2; ++nf) {                                       \
        accR[mf][nf] = __builtin_amdgcn_mfma_f32_16x16x32_bf16(a[mf], br[nf], accR[mf][nf], 0, 0, 0); \
        accI[mf][nf] = __builtin_amdgcn_mfma_f32_16x16x32_bf16(a[mf], bi[nf], accI[mf][nf], 0, 0, 0); \
      } }

  XM_STAGE(0, 0);
  XM_STAGE(1, 32);
  #pragma unroll 1
  for (int t = 0; t < 32; ++t) {
    int bufc = t % 3;
    if (t + 2 < 32) { XM_STAGE((t + 2) % 3, (t + 2) * 32); }
    if (t + 2 < 32)      { WAITV(8); }
    else if (t + 1 < 32) { WAITV(4); }
    else                 { WAITV(0); }
    __builtin_amdgcn_sched_barrier(0);
    __builtin_amdgcn_s_barrier();
    __builtin_amdgcn_s_setprio(1);
    XM_COMPUTE(bufc)
    __builtin_amdgcn_s_setprio(0);
    __builtin_amdgcn_sched_barrier(0);
    __builtin_amdgcn_s_barrier();
  }

  // fused Wo/Wg reduce for this block's (batch, col-range) -> LDS
  float* gl  = (float*)lds;         // [64] gate
  float* prl = gl + 64;             // [64] proj re
  float* pil = prl + 64;            // [64] proj im
  __syncthreads();
  if (tid < 64) {
    int c = bn + tid;
    int b0 = bm >> 8;
    float vg = bg[c];
    float vr = bo[c];
    float vi = bo[1024 + c];
    #pragma unroll
    for (int s = 0; s < 8; ++s) {
      vg += PpG[(size_t)s * 16384 + b0 * 1024 + c];
      vr += PpO[(size_t)s * 32768 + b0 * 2048 + c];
      vi += PpO[(size_t)s * 32768 + b0 * 2048 + 1024 + c];
    }
    gl[tid]  = sigmoidf_(vg);
    prl[tid] = vr;
    pil[tid] = vi;
  }
  __syncthreads();

  #pragma unroll
  for (int mf = 0; mf < 4; ++mf)
    #pragma unroll
    for (int nf = 0; nf < 2; ++nf) {
      int lc = wc * 32 + nf * 16 + (lane & 15);
      int c = bn + lc;
      float g  = gl[lc];
      float sr = prl[lc];
      float si = pil[lc];
      float odr = od_re[c], odi = od_im[c];
      float ofr = of_re[c], ofi = of_im[c];
      #pragma unroll
      for (int r = 0; r < 4; ++r) {
        int t = bm + wr * 64 + mf * 16 + (lane >> 4) * 4 + r;
        float fr = accR[mf][nf][r] * g + sr * (1.0f - g);
        float fi = accI[mf][nf][r] * g + si * (1.0f - g);
        size_t off = (size_t)t * 1024 + c;
        float pr = hp_re[off], pi = hp_im[off];
        Hrb[off] = f2bf(pr * odr - pi * odi + fr * ofr - fi * ofi);
      }
    }
}

// ---------------------------------------------------------------------------
// real NT GEMM, bf16: C = A@B^T.  KI = K/32.  3-buffer counted-vmcnt, BK=32.
// EPI=0 (mlp1): silu->bf16 direct.
// EPI=2 (u): softplus + FUSED fin: out0 = Hrb + nre*sqrt(bvar*u)*sqrt(0.5)
// ---------------------------------------------------------------------------
template<int KI, int EPI>
__global__ __launch_bounds__(TPB) void rgemm_nt_k(
    const u16* __restrict__ A, const u16* __restrict__ B,
    const float* __restrict__ bias,
    u16* __restrict__ C16, int nbxl, int total,
    const u16* __restrict__ HrbF, const float* __restrict__ nre,
    const float* __restrict__ bvarp, float* __restrict__ outp)
{
  __shared__ __align__(16) u16 lds[3 * 2 * PSZ];   // 24KB (ct needs 17.4KB)
  const int K = KI * 32;
  int tid = threadIdx.x;
  int flat = swz8(blockIdx.x, total);
  int bm = (flat >> nbxl) * 64;
  int bn = (flat & ((1 << nbxl) - 1)) * 64;
  const int N = 64 << nbxl;
  int lane = tid & 63;
  int wr = (tid >> 7) & 1, wc = (tid >> 6) & 1;
  int lr_ = ((tid & 63) >> 2) + ((tid >> 6) << 4);
  int ks_ = (((tid & 3) ^ ((tid >> 3) & 3)) << 3);
  u16* Lw_ = lds + ((tid >> 6) << 9);

  f32x4 acc[2][2] = {};

#define RG_STAGE(buf, k0)                                                    \
  { u16* Lb = Lw_ + (buf) * (2 * PSZ);                                       \
    gload16(A + (size_t)(bm + lr_) * K + (k0) + ks_, Lb + 0 * PSZ);          \
    gload16(B + (size_t)(bn + lr_) * K + (k0) + ks_, Lb + 1 * PSZ); }
#define RG_COMPUTE(buf)                                                      \
  { const u16* L = lds + (buf) * (2 * PSZ);                                  \
    int rA = wr * 32 + (lane & 15);                                          \
    int rB = wc * 32 + (lane & 15);                                          \
    int kq = lane >> 4;                                                      \
    bf8v a[2], b[2];                                                         \
    a[0] = fragld(L + 0 * PSZ, rA, kq);  a[1] = fragld(L + 0 * PSZ, rA + 16, kq); \
    b[0] = fragld(L + 1 * PSZ, rB, kq);  b[1] = fragld(L + 1 * PSZ, rB + 16, kq); \
    _Pragma("unroll")                                                        \
    for (int mf = 0; mf < 2; ++mf)                                           \
      _Pragma("unroll")                                                      \
      for (int nf = 0; nf < 2; ++nf)                                         \
        acc[mf][nf] = __builtin_amdgcn_mfma_f32_16x16x32_bf16(a[mf], b[nf], acc[mf][nf], 0, 0, 0); }

  RG_STAGE(0, 0);
  RG_STAGE(1, 32);
  #pragma unroll 1
  for (int t = 0; t < KI; ++t) {
    int bufc = t % 3;
    if (t + 2 < KI) { RG_STAGE((t + 2) % 3, (t + 2) * 32); }
    if (t + 2 < KI)      { WAITV(4); }
    else if (t + 1 < KI) { WAITV(2); }
    else                 { WAITV(0); }
    __builtin_amdgcn_sched_barrier(0);
    __builtin_amdgcn_s_barrier();
    __builtin_amdgcn_s_setprio(1);
    RG_COMPUTE(bufc)
    __builtin_amdgcn_s_setprio(0);
    __builtin_amdgcn_sched_barrier(0);
    __builtin_amdgcn_s_barrier();
  }

  if constexpr (EPI == 0) {
    #pragma unroll
    for (int mf = 0; mf < 2; ++mf)
      #pragma unroll
      for (int nf = 0; nf < 2; ++nf) {
        int c = bn + wc * 32 + nf * 16 + (lane & 15);
        #pragma unroll
        for (int r = 0; r < 4; ++r) {
          int t = bm + wr * 32 + mf * 16 + (lane >> 4) * 4 + r;
          float v = acc[mf][nf][r] + bias[c];
          v = v * sigmoidf_(v);                       // silu (fast exp)
          C16[(size_t)t * N + c] = f2bf(v);
        }
      }
  } else {
    // acc -> LDS f32 tile, then row-contiguous softplus + fused fin -> f32 out
    float* ct = (float*)lds;
    __syncthreads();
    #pragma unroll
    for (int mf = 0; mf < 2; ++mf)
      #pragma unroll
      for (int nf = 0; nf < 2; ++nf) {
        int rbase = wr * 32 + mf * 16 + (lane >> 4) * 4;
        int cc = wc * 32 + nf * 16 + (lane & 15);
        #pragma unroll
        for (int r = 0; r < 4; ++r)
          ct[(rbase + r) * CSTR + cc] = acc[mf][nf][r];
      }
    __syncthreads();
    int w = tid >> 6, l = tid & 63;
    int lcol = (l & 15) * 4;
    const float s2 = 0.7071067811865476f;
    #pragma unroll
    for (int p = 0; p < 4; ++p) {
      int lrow = w * 16 + p * 4 + (l >> 4);
      int t = bm + lrow;
      int c = bn + lcol;
      float4 v4 = *(float4*)&ct[lrow * CSTR + lcol];
      float4 bi4 = *(const float4*)(bias + c);
      float u0 = spf_(v4.x + bi4.x);
      float u1 = spf_(v4.y + bi4.y);
      float u2 = spf_(v4.z + bi4.z);
      float u3 = spf_(v4.w + bi4.w);
      size_t off = (size_t)t * 1024 + c;
      uint2 hb2 = *(const uint2*)(HrbF + off);
      float4 nr4 = *(const float4*)(nre + off);
      float4 bv4 = *(const float4*)(bvarp + c);
      float4 o;
      o.x = bf2f((u16)(hb2.x & 0xFFFF)) + nr4.x * sqrtf(bv4.x * u0) * s2;
      o.y = bf2f((u16)(hb2.x >> 16))    + nr4.y * sqrtf(bv4.y * u1) * s2;
      o.z = bf2f((u16)(hb2.y & 0xFFFF)) + nr4.z * sqrtf(bv4.z * u2) * s2;
      o.w = bf2f((u16)(hb2.y >> 16))    + nr4.w * sqrtf(bv4.w * u3) * s2;
      *(float4*)(outp + off) = o;
    }
  }
}

// ---------------------------------------------------------------------------
extern "C" void kernel_launch(void* const* d_in, const int* in_sizes, int n_in,
                              void* d_out, int out_size, void* d_ws, size_t ws_size,
                              hipStream_t stream) {
  (void)in_sizes; (void)n_in; (void)out_size;

  const float* x_input    = (const float*)d_in[0];
  const float* h_prev_re  = (const float*)d_in[1];
  const float* h_prev_im  = (const float*)d_in[2];
  const float* xg_re      = (const float*)d_in[3];
  const float* xg_im      = (const float*)d_in[4];
  const float* flux_re    = (const float*)d_in[5];
  const float* flux_im    = (const float*)d_in[6];
  const float* dt         = (const float*)d_in[7];
  const float* v_raw_re   = (const float*)d_in[10];
  const float* v_raw_im   = (const float*)d_in[11];
  const float* log_sigma  = (const float*)d_in[12];
  const float* dft_weight = (const float*)d_in[13];
  const float* decay_re   = (const float*)d_in[14];
  const float* decay_im   = (const float*)d_in[15];
  const float* Wi_in      = (const float*)d_in[16];
  const float* bi         = (const float*)d_in[17];
  const float* Wo         = (const float*)d_in[18];
  const float* bo         = (const float*)d_in[19];
  const float* Wg         = (const float*)d_in[20];
  const float* bg         = (const float*)d_in[21];
  const float* ld         = (const float*)d_in[22];
  const float* lf         = (const float*)d_in[23];
  const float* law_re     = (const float*)d_in[24];
  const float* law_im     = (const float*)d_in[25];
  const float* base_noise = (const float*)d_in[26];
  const float* Wu1        = (const float*)d_in[27];
  const float* bu1        = (const float*)d_in[28];
  const float* Wu2        = (const float*)d_in[29];
  const float* bu2        = (const float*)d_in[30];
  const float* noise_re   = (const float*)d_in[31];

  // --- workspace: 16 bf16-sized planes (2MB each) = 32MB --------------------
  const size_t PL16 = 1024ull * 1024ull;        // u16 per plane
  if (ws_size < 16 * PL16 * 2) return;          // too small -> zeros (diagnostic)

  u16* P = (u16*)d_ws;
  // liveness plan (d1..d7 = dispatch order):
  // P0,P1 : Ar,Ai (d1-d2) -> PpO+PpG in P0 (d4-d5)
  // P2,P3 : Nr,Ni (d1-d3) -> Mtr,Mti (d4-d5)
  // P4,P5 : A2 (d2-d3)    -> Hrb P4..P7 (d5-d7)
  // P6,P7 : A4 (d3-d4)    -> Hrb upper
  // P8,P9 : T1 (d3-d4)
  // P10-13: Xb (d2-d5)
  // P14   : PpI (d2-d3)   -> mlp1b (d6-d7)
  // P15   : Wu1b,Wu2b (d2-d7) + sm f32 region
  u16* Ar  = P + 0 * PL16;   u16* Ai  = P + 1 * PL16;
  u16* Nr  = P + 2 * PL16;   u16* Ni  = P + 3 * PL16;
  u16* A2r = P + 4 * PL16;   u16* A2i = P + 5 * PL16;
  u16* A4r = P + 6 * PL16;   u16* A4i = P + 7 * PL16;
  u16* T1r = P + 8 * PL16;   u16* T1i = P + 9 * PL16;
  u16* Mtr = P + 2 * PL16;   u16* Mti = P + 3 * PL16;
  u16* Xb  = P + 10 * PL16;            // P10..P13
  u16* Hrb = P + 4 * PL16;             // P4..P7
  float* PpO = (float*)(P + 0 * PL16); // 1MB
  float* PpG = PpO + 262144;           // 0.5MB (both inside P0)
  float* PpI = (float*)(P + 14 * PL16);// 1MB of P14
  u16* mlp1b = P + 14 * PL16;          // d6+
  u16* Wu1b  = P + 15 * PL16;          // 262144 u16
  u16* Wu2b  = Wu1b + 262144;
  float* sm  = (float*)(P + 15 * PL16 + 524288);
  float* FNr  = sm;                     // 16x1024
  float* FNi  = FNr + 16384;
  float* od_re = FNi + 16384;
  float* od_im = od_re + 1024;
  float* of_re = od_im + 1024;
  float* of_im = of_re + 1024;
  float* bvar  = of_im + 1024;

  float* out0f = (float*)d_out;                       // 4096x1024 f32 (real)
  float* out1f = out0f + (size_t)4096 * 1024;         // 16x1024 f32 (real)

  // d1: A/N build
  build_a_k<<<4096, TPB, 0, stream>>>(v_raw_re, v_raw_im, Ar, Ai, Nr, Ni);
  // d2: A2 gemm (512 x 64x32 tiles) + converts + prep + Wi gemm
  d2_k<<<3076, TPB, 0, stream>>>(Ar, Ai, A2r, A2i,
                                 x_input, Wu1, Wu2,
                                 ld, lf, law_re, law_im, dt, base_noise,
                                 Xb, Wu1b, Wu2b,
                                 od_re, od_im, of_re, of_im, bvar,
                                 xg_re, xg_im, Wi_in, PpI);
  // d3: pair (A4, T1) + fused Wi-reduce+flux
  d3_k<<<576, TPB, 0, stream>>>(A2r, A2i, Nr, Ni, A4r, A4i, T1r, T1i,
                                PpI, bi, flux_re, flux_im, decay_re, decay_im,
                                FNr, FNi, out1f);
  // d4: vmt (Mt build) + Wo/Wg gemm filler
  d4_k<<<896, TPB, 0, stream>>>(T1r, T1i, A4r, A4i, log_sigma, dft_weight,
                                Mtr, Mti,
                                FNr, FNi, Wo, Wg, PpO, PpG);
  // d5: x_tilde @ M + h_next epilogue (fused Wo/Wg reduce, BK=32 3-buffer)
  xmh_nt_k<<<512, TPB, 0, stream>>>(Xb, Mtr, Mti, PpO, PpG, bo, bg,
                                    od_re, od_im, of_re, of_im,
                                    h_prev_re, h_prev_im, Hrb);
  // d6: u-MLP layer 1 ; d7: u-MLP layer 2 + fused fin -> out0
  rgemm_nt_k<32, 0><<<256, TPB, 0, stream>>>(Hrb, Wu1b, bu1, mlp1b, 2, 256,
                                             nullptr, nullptr, nullptr, nullptr);
  rgemm_nt_k<8, 2><<<1024, TPB, 0, stream>>>(mlp1b, Wu2b, bu2, nullptr, 4, 1024,
                                             Hrb, noise_re, bvar, out0f);
}

// Round 29
// 119.339 us; speedup vs baseline: 1.0291x; 1.0291x over previous
//
#include <hip/hip_runtime.h>
#include <cstddef>

#define TPB 256

typedef short bf8v  __attribute__((ext_vector_type(8)));   // 8 bf16 bit-patterns
typedef float f32x4 __attribute__((ext_vector_type(4)));
typedef unsigned short u16;

#define PSZ 2048     // u16 per LDS plane [64][32] (rgemm staging)
#define PSZ2 4096    // u16 per LDS plane [64][64] (BK=64 staging)
#define LSTR 40      // stride for sgemm16 staging
#define BUF1 2560
#define CSTR 68      // f32 LDS epilogue-tile row stride
#define RTBUF 12288  // u16 per retiled buffer: A 2x[64][64] + B 2x[32][64]

static __device__ __forceinline__ u16 f2bf(float x) {
  unsigned int u = __float_as_uint(x);
  u = (u + 0x7FFFu + ((u >> 16) & 1u)) >> 16;   // RNE f32 -> bf16
  return (u16)u;
}
static __device__ __forceinline__ float bf2f(u16 x) {
  return __uint_as_float(((unsigned int)x) << 16);
}
static __device__ __forceinline__ float sigmoidf_(float x) {
  return 1.0f / (1.0f + __expf(-x));            // fast exp (v_exp_f32)
}
static __device__ __forceinline__ float spf_(float v) {   // fast softplus
  return (v > 15.0f) ? v : __logf(1.0f + __expf(v));
}
static __device__ __forceinline__ bf8v neg8(bf8v a) {
  #pragma unroll
  for (int i = 0; i < 8; ++i) a[i] ^= (short)0x8000;
  return a;
}
static __device__ __forceinline__ void pack8(const float4& x, const float4& y,
                                             u16* dst) {
  unsigned int* d = (unsigned int*)dst;
  d[0] = ((unsigned)f2bf(x.y) << 16) | f2bf(x.x);
  d[1] = ((unsigned)f2bf(x.w) << 16) | f2bf(x.z);
  d[2] = ((unsigned)f2bf(y.y) << 16) | f2bf(y.x);
  d[3] = ((unsigned)f2bf(y.w) << 16) | f2bf(y.z);
}
static __device__ __forceinline__ uint2 packbf4(float a, float b, float c, float d) {
  uint2 r;
  r.x = ((unsigned)f2bf(b) << 16) | f2bf(a);
  r.y = ((unsigned)f2bf(d) << 16) | f2bf(c);
  return r;
}
// async global->LDS, 16B per lane; LDS dest is wave-uniform base + lane*16
static __device__ __forceinline__ void gload16(const u16* g, u16* l) {
  __builtin_amdgcn_global_load_lds((const __attribute__((address_space(1))) void*)g,
                                   (__attribute__((address_space(3))) void*)l,
                                   16, 0, 0);
}
// BK=32 fragment read with k-chunk XOR swizzle (rgemm path)
static __device__ __forceinline__ bf8v fragld(const u16* plane, int r, int kq) {
  int kb = (kq << 4) ^ (((r >> 1) & 3) << 4);
  return *(const bf8v*)(plane + r * 32 + (kb >> 1));
}
// BK=64 fragment read: global chunk (s*4+kq) at row r lives at chunk^(r&7)
static __device__ __forceinline__ bf8v fragld2(const u16* plane, int r, int kq, int s) {
  int ch = ((s << 2) + kq) ^ (r & 7);
  return *(const bf8v*)(plane + r * 64 + (ch << 3));
}
// XCD-aware bijective block swizzle (T % 8 == 0)
static __device__ __forceinline__ int swz8(int flat, int T) {
  return (flat & 7) * (T >> 3) + (flat >> 3);
}

#define WAITV(n) asm volatile("s_waitcnt vmcnt(" #n ")" ::: "memory")

// ---------------------------------------------------------------------------
// A = (v - v^T)re + i(v + v^T)im ; N = I - A   -> bf16 planes
// ---------------------------------------------------------------------------
__global__ __launch_bounds__(TPB) void build_a_k(
    const float* __restrict__ vre, const float* __restrict__ vim,
    u16* __restrict__ Ar, u16* __restrict__ Ai,
    u16* __restrict__ Nr, u16* __restrict__ Ni)
{
  int idx = blockIdx.x * TPB + threadIdx.x;
  int i = idx >> 10, j = idx & 1023;
  float ar = vre[idx] - vre[j * 1024 + i];
  float ai = vim[idx] + vim[j * 1024 + i];
  float dg = (i == j) ? 1.0f : 0.0f;
  Ar[idx] = f2bf(ar);       Ai[idx] = f2bf(ai);
  Nr[idx] = f2bf(dg - ar);  Ni[idx] = f2bf(-ai);
}

// ---------------------------------------------------------------------------
// complex-NT, BK=64.  4-wave 64x64 (pair) and 4-wave 64x32 retile (a2/vmt).
// ---------------------------------------------------------------------------
#define CG_VARS                                                              \
  int lane = tid & 63;                                                       \
  int wr = (tid >> 7) & 1, wc = (tid >> 6) & 1;                              \
  int lr8_ = ((tid & 63) >> 3) + ((tid >> 6) << 4);                          \
  int ks2_ = (((lane & 7) ^ (lane >> 3)) << 3);                              \
  u16* Lw_ = lds + ((tid >> 6) << 10);                                       \
  f32x4 accR[2][2] = {};                                                     \
  f32x4 accI[2][2] = {};

#define CG_STAGE(buf, k0, PAr, PAi, PBr, PBi)                                \
  { u16* Lb = Lw_ + (buf) * (4 * PSZ2);                                      \
    gload16((PAr) + (size_t)(bm + lr8_) * 1024 + (k0) + ks2_,     Lb + 0 * PSZ2);       \
    gload16((PAr) + (size_t)(bm + lr8_ + 8) * 1024 + (k0) + ks2_, Lb + 0 * PSZ2 + 512); \
    gload16((PAi) + (size_t)(bm + lr8_) * 1024 + (k0) + ks2_,     Lb + 1 * PSZ2);       \
    gload16((PAi) + (size_t)(bm + lr8_ + 8) * 1024 + (k0) + ks2_, Lb + 1 * PSZ2 + 512); \
    gload16((PBr) + (size_t)(bn + lr8_) * 1024 + (k0) + ks2_,     Lb + 2 * PSZ2);       \
    gload16((PBr) + (size_t)(bn + lr8_ + 8) * 1024 + (k0) + ks2_, Lb + 2 * PSZ2 + 512); \
    gload16((PBi) + (size_t)(bn + lr8_) * 1024 + (k0) + ks2_,     Lb + 3 * PSZ2);       \
    gload16((PBi) + (size_t)(bn + lr8_ + 8) * 1024 + (k0) + ks2_, Lb + 3 * PSZ2 + 512); }

#define CG_FRAGS(buf, s)                                                     \
  const u16* L = lds + (buf) * (4 * PSZ2);                                   \
  int rA = wr * 32 + (lane & 15);                                            \
  int rB = wc * 32 + (lane & 15);                                            \
  int kq = lane >> 4;                                                        \
  bf8v ar[2], ai[2], br[2], bi[2];                                           \
  ar[0] = fragld2(L + 0 * PSZ2, rA, kq, s);  ar[1] = fragld2(L + 0 * PSZ2, rA + 16, kq, s); \
  ai[0] = fragld2(L + 1 * PSZ2, rA, kq, s);  ai[1] = fragld2(L + 1 * PSZ2, rA + 16, kq, s); \
  br[0] = fragld2(L + 2 * PSZ2, rB, kq, s);  br[1] = fragld2(L + 2 * PSZ2, rB + 16, kq, s); \
  bi[0] = fragld2(L + 3 * PSZ2, rB, kq, s);  bi[1] = fragld2(L + 3 * PSZ2, rB + 16, kq, s);

#define CG_MFMA_BNEG1                                                        \
  { bf8v nbi[2] = { neg8(bi[0]), neg8(bi[1]) };                              \
    _Pragma("unroll")                                                        \
    for (int mf = 0; mf < 2; ++mf)                                           \
      _Pragma("unroll")                                                      \
      for (int nf = 0; nf < 2; ++nf) {                                       \
        accR[mf][nf] = __builtin_amdgcn_mfma_f32_16x16x32_bf16(ar[mf], br[nf],  accR[mf][nf], 0, 0, 0); \
        accR[mf][nf] = __builtin_amdgcn_mfma_f32_16x16x32_bf16(ai[mf], bi[nf],  accR[mf][nf], 0, 0, 0); \
        accI[mf][nf] = __builtin_amdgcn_mfma_f32_16x16x32_bf16(ar[mf], nbi[nf], accI[mf][nf], 0, 0, 0); \
        accI[mf][nf] = __builtin_amdgcn_mfma_f32_16x16x32_bf16(ai[mf], br[nf],  accI[mf][nf], 0, 0, 0); \
      } }

#define CG_PIPELINE(MFMA_OP, PAr, PAi, PBr, PBi)                             \
  CG_STAGE(0, 0, PAr, PAi, PBr, PBi);                                        \
  _Pragma("unroll 1")                                                        \
  for (int t = 0; t < 16; ++t) {                                             \
    int bufc = t & 1;                                                        \
    if (t + 1 < 16) { CG_STAGE(bufc ^ 1, (t + 1) * 64, PAr, PAi, PBr, PBi);  \
                      WAITV(8); }                                            \
    else            { WAITV(0); }                                            \
    __builtin_amdgcn_sched_barrier(0);                                       \
    __builtin_amdgcn_s_barrier();                                            \
    __builtin_amdgcn_s_setprio(1);                                           \
    { CG_FRAGS(bufc, 0) MFMA_OP }                                            \
    { CG_FRAGS(bufc, 1) MFMA_OP }                                            \
    __builtin_amdgcn_s_setprio(0);                                           \
    __builtin_amdgcn_sched_barrier(0);                                       \
    __builtin_amdgcn_s_barrier();                                            \
  }

// ---- 64x32 retile, 4 waves (TPB): wave = wr (m-half) x wc (n-half of 32) --
// LDS buffer: Ar [64][64] @0, Ai @4096, Br [32][64] @8192, Bi @10240 (u16)
#define CGRT_VARS                                                            \
  int lane = tid & 63;                                                       \
  int wv = tid >> 6;                                                         \
  int wr = wv >> 1, wc = wv & 1;                                             \
  int ln8 = lane >> 3;                                                       \
  int ks2_ = (((lane & 7) ^ ln8) << 3);                                      \
  f32x4 accR[2] = {};                                                        \
  f32x4 accI[2] = {};

#define CGRT_STAGE(buf, k0, PAr, PAi, PBr, PBi)                              \
  { u16* Lb = lds + (buf) * RTBUF;                                           \
    _Pragma("unroll")                                                        \
    for (int j = 0; j < 6; ++j) {                                            \
      int idx = wv * 6 + j;                                                  \
      const u16* src; int row; int doff;                                     \
      if (idx < 16) {                                                        \
        int pl = idx >> 3, gr = idx & 7;                                     \
        src = pl ? (PAi) : (PAr);                                            \
        row = bm + gr * 8 + ln8;                                             \
        doff = pl * 4096 + gr * 512;                                         \
      } else {                                                               \
        int i2 = idx - 16;                                                   \
        int pl = i2 >> 2, gr = i2 & 3;                                       \
        src = pl ? (PBi) : (PBr);                                            \
        row = bn + gr * 8 + ln8;                                             \
        doff = 8192 + pl * 2048 + gr * 512;                                  \
      }                                                                      \
      gload16(src + (size_t)row * 1024 + (k0) + ks2_, Lb + doff);            \
    } }

#define CGRT_FRAGS(buf, s)                                                   \
  const u16* L = lds + (buf) * RTBUF;                                        \
  int rA = wr * 32 + (lane & 15);                                            \
  int rB = wc * 16 + (lane & 15);                                            \
  int kq = lane >> 4;                                                        \
  bf8v ar[2], ai[2], br1, bi1;                                               \
  ar[0] = fragld2(L, rA, kq, s);          ar[1] = fragld2(L, rA + 16, kq, s);          \
  ai[0] = fragld2(L + 4096, rA, kq, s);   ai[1] = fragld2(L + 4096, rA + 16, kq, s);   \
  br1 = fragld2(L + 8192, rB, kq, s);                                        \
  bi1 = fragld2(L + 10240, rB, kq, s);

#define CGRT_MFMA_BNEG0                                                      \
  { bf8v nbr = neg8(br1);                                                    \
    bf8v nbi = neg8(bi1);                                                    \
    _Pragma("unroll")                                                        \
    for (int mf = 0; mf < 2; ++mf) {                                         \
      accR[mf] = __builtin_amdgcn_mfma_f32_16x16x32_bf16(ar[mf], nbr, accR[mf], 0, 0, 0); \
      accR[mf] = __builtin_amdgcn_mfma_f32_16x16x32_bf16(ai[mf], nbi, accR[mf], 0, 0, 0); \
      accI[mf] = __builtin_amdgcn_mfma_f32_16x16x32_bf16(ar[mf], bi1, accI[mf], 0, 0, 0); \
      accI[mf] = __builtin_amdgcn_mfma_f32_16x16x32_bf16(ai[mf], nbr, accI[mf], 0, 0, 0); \
    } }

#define CGRT_MFMA_BNEG1                                                      \
  { bf8v nbi = neg8(bi1);                                                    \
    _Pragma("unroll")                                                        \
    for (int mf = 0; mf < 2; ++mf) {                                         \
      accR[mf] = __builtin_amdgcn_mfma_f32_16x16x32_bf16(ar[mf], br1, accR[mf], 0, 0, 0); \
      accR[mf] = __builtin_amdgcn_mfma_f32_16x16x32_bf16(ai[mf], bi1, accR[mf], 0, 0, 0); \
      accI[mf] = __builtin_amdgcn_mfma_f32_16x16x32_bf16(ar[mf], nbi, accI[mf], 0, 0, 0); \
      accI[mf] = __builtin_amdgcn_mfma_f32_16x16x32_bf16(ai[mf], br1, accI[mf], 0, 0, 0); \
    } }

#define CGRT_PIPELINE(MFMA_OP, PAr, PAi, PBr, PBi)                           \
  CGRT_STAGE(0, 0, PAr, PAi, PBr, PBi);                                      \
  _Pragma("unroll 1")                                                        \
  for (int t = 0; t < 16; ++t) {                                             \
    int bufc = t & 1;                                                        \
    if (t + 1 < 16) { CGRT_STAGE(bufc ^ 1, (t + 1) * 64, PAr, PAi, PBr, PBi);\
                      WAITV(6); }                                            \
    else            { WAITV(0); }                                            \
    __builtin_amdgcn_sched_barrier(0);                                       \
    __builtin_amdgcn_s_barrier();                                            \
    __builtin_amdgcn_s_setprio(1);                                           \
    { CGRT_FRAGS(bufc, 0) MFMA_OP }                                          \
    { CGRT_FRAGS(bufc, 1) MFMA_OP }                                          \
    __builtin_amdgcn_s_setprio(0);                                           \
    __builtin_amdgcn_sched_barrier(0);                                       \
    __builtin_amdgcn_s_barrier();                                            \
  }

// ---------------------------------------------------------------------------
// d2: bx<512: A2=A@A 64x32 retile | [512,2816): converts | [2816,2820): prep
//     [2820,3076): sgemm16 Wi
// ---------------------------------------------------------------------------
__global__ __launch_bounds__(TPB) void d2_k(
    const u16* __restrict__ Apr, const u16* __restrict__ Api,
    u16* __restrict__ A2r, u16* __restrict__ A2i,
    const float* __restrict__ X, const float* __restrict__ Wu1,
    const float* __restrict__ Wu2,
    const float* __restrict__ ld, const float* __restrict__ lf,
    const float* __restrict__ law_re, const float* __restrict__ law_im,
    const float* __restrict__ dt, const float* __restrict__ base_noise,
    u16* __restrict__ Xb, u16* __restrict__ Wu1b, u16* __restrict__ Wu2b,
    float* __restrict__ od_re, float* __restrict__ od_im,
    float* __restrict__ of_re, float* __restrict__ of_im,
    float* __restrict__ bvar,
    const float* __restrict__ xg_re, const float* __restrict__ xg_im,
    const float* __restrict__ Wi, float* __restrict__ PpI)
{
  __shared__ __align__(16) u16 lds[2 * RTBUF];          // 48KB
  int tid = threadIdx.x;
  int bx = blockIdx.x;
  if (bx < 512) {
    int flat = swz8(bx, 512);
    int bm = (flat >> 5) * 64, bn = (flat & 31) * 32;
    CGRT_VARS
    CGRT_PIPELINE(CGRT_MFMA_BNEG0, Apr, Api, Apr, Api)
    #pragma unroll
    for (int mf = 0; mf < 2; ++mf) {
      int col = bn + wc * 16 + (lane & 15);
      #pragma unroll
      for (int r = 0; r < 4; ++r) {
        int rowg = bm + wr * 32 + mf * 16 + (lane >> 4) * 4 + r;
        size_t o = (size_t)rowg * 1024 + col;
        A2r[o] = f2bf(accR[mf][r]);
        A2i[o] = f2bf(accI[mf][r]);
      }
    }
  } else if (bx < 2816) {
    int e = ((bx - 512) * TPB + tid) << 3;
    const float* src;
    u16* dst;
    if (e < 4194304)       { src = X + e;               dst = Xb + e; }
    else if (e < 4456448)  { src = Wu1 + (e - 4194304); dst = Wu1b + (e - 4194304); }
    else                   { src = Wu2 + (e - 4456448); dst = Wu2b + (e - 4456448); }
    float4 a = *(const float4*)src;
    float4 b = *(const float4*)(src + 4);
    u16 tmp[8];
    pack8(a, b, tmp);
    *(bf8v*)dst = *(bf8v*)tmp;
  } else if (bx < 2820) {
    int d = (bx - 2816) * TPB + tid;                    // 0..1023
    float dtr = dt[0];                                  // DT_REF = 1.0
    float lre = tanhf(-expf(ld[d]) + law_re[d]) * 0.3f;
    float lim = lf[d] + law_im[d];
    float er = expf(lre * dtr);
    float sn, cs;
    sincosf(lim * dtr, &sn, &cs);
    float odr = er * cs, odi = er * sn;
    od_re[d] = odr;  od_im[d] = odi;
    float numr = odr - 1.0f, numi = odi;
    float denr = lre + 1e-8f, deni = lim;
    float inv = 1.0f / (denr * denr + deni * deni);
    of_re[d] = (numr * denr + numi * deni) * inv;
    of_im[d] = (numi * denr - numr * deni) * inv;
    float bn2 = base_noise[0];
    float bv = bn2 * bn2 * expm1f(2.0f * lre * dtr) / (2.0f * lre + 1e-8f);
    bvar[d] = fmaxf(bv, 0.0f);
  } else {
    // sgemm16 Wi: M=16 split-K partials
    int id = bx - 2820;
    int c0 = (id & 31) * 64;
    int kbase = (id >> 5) * 256;
    int lane = tid & 63;
    int w = tid >> 6;
    int row = tid >> 2, kq = (tid & 3) << 3;

    f32x4 acc = {};
    float4 pb0, pb1;
    u16* sl = lds;

    auto gload = [&](int k0) {
      const float* p = Wi + (size_t)(c0 + row) * 2048 + k0 + kq;
      pb0 = *(const float4*)p; pb1 = *(const float4*)(p + 4);
    };
    auto stolds = [&](int buf) {
      pack8(pb0, pb1, sl + buf * BUF1 + row * LSTR + kq);
    };
    auto compute = [&](int buf, int k0) {
      int ar = lane & 15;
      int ko = (lane >> 4) * 8;
      const float* ap = (k0 < 1024) ? (xg_re + (size_t)ar * 1024 + k0 + ko)
                                    : (xg_im + (size_t)ar * 1024 + k0 + ko - 1024);
      float4 a0 = *(const float4*)ap, a1 = *(const float4*)(ap + 4);
      u16 abuf[8];
      pack8(a0, a1, abuf);
      bf8v af = *(bf8v*)abuf;
      bf8v bfr = *(const bf8v*)(sl + buf * BUF1 + (w * 16 + (lane & 15)) * LSTR + ko);
      acc = __builtin_amdgcn_mfma_f32_16x16x32_bf16(af, bfr, acc, 0, 0, 0);
    };

    gload(kbase); stolds(0); __syncthreads();
    int cur = 0;
    for (int t = 0; t < 8; ++t) {
      int k0 = kbase + t * 32;
      if (t < 7) gload(k0 + 32);
      compute(cur, k0);
      if (t < 7) stolds(cur ^ 1);
      __syncthreads();
      cur ^= 1;
    }
    int c = c0 + w * 16 + (lane & 15);
    #pragma unroll
    for (int r = 0; r < 4; ++r) {
      int rr = (lane >> 4) * 4 + r;
      PpI[((size_t)(id >> 5) * 16 + rr) * 2048 + c] = acc[r];
    }
  }
}

// ---------------------------------------------------------------------------
// d3: bx<512: batched pair (z=0: A4=A2@A2 ; z=1: T1=N@A2+N)
//     [512,576): fused red16(Wi) + flux -> FNr/FNi/out1
// ---------------------------------------------------------------------------
__global__ __launch_bounds__(TPB) void d3_k(
    const u16* __restrict__ A2r, const u16* __restrict__ A2i,
    const u16* __restrict__ Nr2, const u16* __restrict__ Ni2,
    u16* __restrict__ A4r, u16* __restrict__ A4i,
    u16* __restrict__ T1r, u16* __restrict__ T1i,
    const float* __restrict__ PpI, const float* __restrict__ bi,
    const float* __restrict__ flux_re, const float* __restrict__ flux_im,
    const float* __restrict__ decay_re, const float* __restrict__ decay_im,
    float* __restrict__ FNr, float* __restrict__ FNi,
    float* __restrict__ out1)
{
  __shared__ __align__(16) u16 lds[2 * 4 * PSZ2];       // 64KB
  int tid = threadIdx.x;
  int bx = blockIdx.x;
  if (bx < 512) {
    int flat = swz8(bx, 512);
    int z = flat >> 8;
    int t8 = flat & 255;
    int bm = (t8 >> 4) * 64, bn = (t8 & 15) * 64;
    const u16* Apr = z ? Nr2 : A2r;
    const u16* Api = z ? Ni2 : A2i;
    u16* Cr16 = z ? T1r : A4r;
    u16* Ci16 = z ? T1i : A4i;
    CG_VARS
    CG_PIPELINE(CG_MFMA_BNEG1, Apr, Api, A2r, A2i)
    #pragma unroll
    for (int mf = 0; mf < 2; ++mf)
      #pragma unroll
      for (int nf = 0; nf < 2; ++nf) {
        int col = bn + wc * 32 + nf * 16 + (lane & 15);
        #pragma unroll
        for (int r = 0; r < 4; ++r) {
          int rowg = bm + wr * 32 + mf * 16 + (lane >> 4) * 4 + r;
          size_t o = (size_t)rowg * 1024 + col;
          float vr = accR[mf][nf][r], vi = accI[mf][nf][r];
          if (z) { vr += bf2f(Nr2[o]); vi += bf2f(Ni2[o]); }   // +N
          Cr16[o] = f2bf(vr);
          Ci16[o] = f2bf(vi);
        }
      }
  } else {
    int idx = (bx - 512) * TPB + tid;   // 16 * 1024
    int b = idx >> 10, d = idx & 1023;
    float ur = bi[d];
    float ui = bi[1024 + d];
    #pragma unroll
    for (int s = 0; s < 8; ++s) {
      ur += PpI[(size_t)s * 32768 + b * 2048 + d];
      ui += PpI[(size_t)s * 32768 + b * 2048 + 1024 + d];
    }
    float fdr = sigmoidf_(decay_re[d]);
    float fdi = decay_im[d];
    float fr = flux_re[idx], fi = flux_im[idx];
    float nr = fr * fdr - fi * fdi + ur;
    float ni = fr * fdi + fi * fdr + ui;
    FNr[idx] = nr;  FNi[idx] = ni;
    out1[idx] = nr;                                // f32, real part only
  }
}

// ---------------------------------------------------------------------------
// d4: bx<512: V = 2*(T1@A4)+2*T1-I fused Mt build (64x32 retile)
//     [512,896): sgemm16 Wo+Wg split-K partials (filler under vmt stalls)
// ---------------------------------------------------------------------------
__global__ __launch_bounds__(TPB) void d4_k(
    const u16* __restrict__ T1r, const u16* __restrict__ T1i,
    const u16* __restrict__ A4r, const u16* __restrict__ A4i,
    const float* __restrict__ log_sigma, const float* __restrict__ dft_weight,
    u16* __restrict__ Mtr, u16* __restrict__ Mti,
    const float* __restrict__ FNr, const float* __restrict__ FNi,
    const float* __restrict__ Wo, const float* __restrict__ Wg,
    float* __restrict__ PpO, float* __restrict__ PpG)
{
  __shared__ __align__(16) u16 lds[2 * RTBUF];          // 48KB
  int tid = threadIdx.x;
  int bx = blockIdx.x;
  if (bx < 512) {
    int flat = swz8(bx, 512);
    int bm = (flat >> 5) * 64, bn = (flat & 31) * 32;   // bm=k-range, bn=d-range
    CGRT_VARS
    CGRT_PIPELINE(CGRT_MFMA_BNEG1, T1r, T1i, A4r, A4i)

    // fused Mt epilogue: compute in (k,d) position, transpose via LDS u16 tiles
    u16* mtLr = lds;              // [32][72] u16
    u16* mtLi = lds + 2304;
    __syncthreads();
    {
      float alpha = sigmoidf_(dft_weight[0]);
      const float isq = 0.03125f * alpha;
      #pragma unroll
      for (int mf = 0; mf < 2; ++mf) {
        int dl = wc * 16 + (lane & 15);               // local d (0..31)
        int dgl = bn + dl;                            // global d
        float w1 = expf(log_sigma[dgl]) * (1.0f - alpha);
        #pragma unroll
        for (int r = 0; r < 4; ++r) {
          int kl = wr * 32 + mf * 16 + (lane >> 4) * 4 + r;   // local k (0..63)
          int kgl = bm + kl;                                  // global k
          size_t o = (size_t)kgl * 1024 + dgl;
          float dg = (kgl == dgl) ? 1.0f : 0.0f;
          float vr = 2.0f * accR[mf][r] + 2.0f * bf2f(T1r[o]) - dg;
          float vi = 2.0f * accI[mf][r] + 2.0f * bf2f(T1i[o]);
          int mm = (kgl * dgl) & 1023;
          float ang = -6.283185307179586f * (float)mm * (1.0f / 1024.0f);
          float sn, cs;
          sincosf(ang, &sn, &cs);
          mtLr[dl * 72 + kl] = f2bf(vr * w1 + cs * isq);
          mtLi[dl * 72 + kl] = f2bf(vi * w1 + sn * isq);
        }
      }
    }
    __syncthreads();
    {
      int dl = tid >> 3, kl0 = (tid & 7) * 8;
      size_t o = (size_t)(bn + dl) * 1024 + bm + kl0;
      *(uint4*)(Mtr + o) = *(uint4*)(mtLr + dl * 72 + kl0);
      *(uint4*)(Mti + o) = *(uint4*)(mtLi + dl * 72 + kl0);
    }
  } else {
    // sgemm16 Wo+Wg: id in [0,384): c-block = id%48, k-chunk = id/48
    int id = bx - 512;
    int cb = id % 48;
    int ky = id / 48;
    const float* Bw = (cb < 32) ? Wo : Wg;
    float* Pp = (cb < 32) ? PpO : PpG;
    int N = (cb < 32) ? 2048 : 1024;
    int c0 = ((cb < 32) ? cb : (cb - 32)) * 64;
    int kbase = ky * 256;
    int lane = tid & 63;
    int w = tid >> 6;
    int row = tid >> 2, kq = (tid & 3) << 3;

    f32x4 acc = {};
    float4 pb0, pb1;
    u16* sl = lds;

    auto gload = [&](int k0) {
      const float* p = Bw + (size_t)(c0 + row) * 2048 + k0 + kq;
      pb0 = *(const float4*)p; pb1 = *(const float4*)(p + 4);
    };
    auto stolds = [&](int buf) {
      pack8(pb0, pb1, sl + buf * BUF1 + row * LSTR + kq);
    };
    auto compute = [&](int buf, int k0) {
      int ar = lane & 15;
      int ko = (lane >> 4) * 8;
      const float* ap = (k0 < 1024) ? (FNr + (size_t)ar * 1024 + k0 + ko)
                                    : (FNi + (size_t)ar * 1024 + k0 + ko - 1024);
      float4 a0 = *(const float4*)ap, a1 = *(const float4*)(ap + 4);
      u16 abuf[8];
      pack8(a0, a1, abuf);
      bf8v af = *(bf8v*)abuf;
      bf8v bfr = *(const bf8v*)(sl + buf * BUF1 + (w * 16 + (lane & 15)) * LSTR + ko);
      acc = __builtin_amdgcn_mfma_f32_16x16x32_bf16(af, bfr, acc, 0, 0, 0);
    };

    gload(kbase); stolds(0); __syncthreads();
    int cur = 0;
    for (int t = 0; t < 8; ++t) {
      int k0 = kbase + t * 32;
      if (t < 7) gload(k0 + 32);
      compute(cur, k0);
      if (t < 7) stolds(cur ^ 1);
      __syncthreads();
      cur ^= 1;
    }
    int c = c0 + w * 16 + (lane & 15);
    #pragma unroll
    for (int r = 0; r < 4; ++r) {
      int rr = (lane >> 4) * 4 + r;
      Pp[((size_t)ky * 16 + rr) * N + c] = acc[r];
    }
  }
}

// ---------------------------------------------------------------------------
// x_tilde = Xb @ M + h_next epilogue -> Hrb bf16.  Fused Wo/Wg reduce:
// gate/proj computed in-block from PpO/PpG partials (same order as red16).
// 128x64 tile, 4 waves each computing 64x32 (mf=4, nf=2). BK=64, 2-buffer.
// ---------------------------------------------------------------------------
__global__ __launch_bounds__(TPB) void xmh_nt_k(
    const u16* __restrict__ Xb,
    const u16* __restrict__ Mtr, const u16* __restrict__ Mti,
    const float* __restrict__ PpO, const float* __restrict__ PpG,
    const float* __restrict__ bo, const float* __restrict__ bg,
    const float* __restrict__ od_re, const float* __restrict__ od_im,
    const float* __restrict__ of_re, const float* __restrict__ of_im,
    const float* __restrict__ hp_re, const float* __restrict__ hp_im,
    u16* __restrict__ Hrb)
{
  __shared__ __align__(16) u16 lds[2 * 16384];        // 64KB
  int flat = swz8(blockIdx.x, 512);
  int bm = (flat >> 4) * 128, bn = (flat & 15) * 64;
  int tid = threadIdx.x;
  int lane = tid & 63;
  int w = tid >> 6;
  int wr = w >> 1, wc = w & 1;
  int ln8 = lane >> 3;
  int ks2_ = (((lane & 7) ^ ln8) << 3);

  f32x4 accR[4][2] = {};
  f32x4 accI[4][2] = {};

#define XM_STAGE(buf, k0)                                                    \
  { u16* Lb = lds + (buf) * 16384;                                           \
    _Pragma("unroll")                                                        \
    for (int g = 0; g < 4; ++g)                                              \
      gload16(Xb + (size_t)(bm + w * 32 + g * 8 + ln8) * 1024 + (k0) + ks2_, \
              Lb + (w * 32 + g * 8) * 64);                                   \
    _Pragma("unroll")                                                        \
    for (int g = 0; g < 2; ++g) {                                            \
      gload16(Mtr + (size_t)(bn + w * 16 + g * 8 + ln8) * 1024 + (k0) + ks2_,\
              Lb + 8192 + (w * 16 + g * 8) * 64);                            \
      gload16(Mti + (size_t)(bn + w * 16 + g * 8 + ln8) * 1024 + (k0) + ks2_,\
              Lb + 12288 + (w * 16 + g * 8) * 64);                           \
    } }
#define XM_COMPUTE(buf, s)                                                   \
  { const u16* L = lds + (buf) * 16384;                                      \
    int kq = lane >> 4;                                                      \
    bf8v a[4], br[2], bi[2];                                                 \
    _Pragma("unroll")                                                        \
    for (int mf = 0; mf < 4; ++mf)                                           \
      a[mf] = fragld2(L, wr * 64 + mf * 16 + (lane & 15), kq, s);            \
    _Pragma("unroll")                                                        \
    for (int nf = 0; nf < 2; ++nf) {                                         \
      br[nf] = fragld2(L + 8192,  wc * 32 + nf * 16 + (lane & 15), kq, s);   \
      bi[nf] = fragld2(L + 12288, wc * 32 + nf * 16 + (lane & 15), kq, s);   \
    }                                                                        \
    _Pragma("unroll")                                                        \
    for (int mf = 0; mf < 4; ++mf)                                           \
      _Pragma("unroll")                                                      \
      for (int nf = 0; nf < 2; ++nf) {                                       \
        accR[mf][nf] = __builtin_amdgcn_mfma_f32_16x16x32_bf16(a[mf], br[nf], accR[mf][nf], 0, 0, 0); \
        accI[mf][nf] = __builtin_amdgcn_mfma_f32_16x16x32_bf16(a[mf], bi[nf], accI[mf][nf], 0, 0, 0); \
      } }

  XM_STAGE(0, 0);
  #pragma unroll 1
  for (int t = 0; t < 16; ++t) {
    int bufc = t & 1;
    if (t + 1 < 16) { XM_STAGE(bufc ^ 1, (t + 1) * 64); WAITV(8); }
    else            { WAITV(0); }
    __builtin_amdgcn_sched_barrier(0);
    __builtin_amdgcn_s_barrier();
    __builtin_amdgcn_s_setprio(1);
    XM_COMPUTE(bufc, 0)
    XM_COMPUTE(bufc, 1)
    __builtin_amdgcn_s_setprio(0);
    __builtin_amdgcn_sched_barrier(0);
    __builtin_amdgcn_s_barrier();
  }

  // fused Wo/Wg reduce for this block's (batch, col-range) -> LDS
  float* gl  = (float*)lds;         // [64] gate
  float* prl = gl + 64;             // [64] proj re
  float* pil = prl + 64;            // [64] proj im
  __syncthreads();
  if (tid < 64) {
    int c = bn + tid;
    int b0 = bm >> 8;
    float vg = bg[c];
    float vr = bo[c];
    float vi = bo[1024 + c];
    #pragma unroll
    for (int s = 0; s < 8; ++s) {
      vg += PpG[(size_t)s * 16384 + b0 * 1024 + c];
      vr += PpO[(size_t)s * 32768 + b0 * 2048 + c];
      vi += PpO[(size_t)s * 32768 + b0 * 2048 + 1024 + c];
    }
    gl[tid]  = sigmoidf_(vg);
    prl[tid] = vr;
    pil[tid] = vi;
  }
  __syncthreads();

  #pragma unroll
  for (int mf = 0; mf < 4; ++mf)
    #pragma unroll
    for (int nf = 0; nf < 2; ++nf) {
      int lc = wc * 32 + nf * 16 + (lane & 15);
      int c = bn + lc;
      float g  = gl[lc];
      float sr = prl[lc];
      float si = pil[lc];
      float odr = od_re[c], odi = od_im[c];
      float ofr = of_re[c], ofi = of_im[c];
      #pragma unroll
      for (int r = 0; r < 4; ++r) {
        int t = bm + wr * 64 + mf * 16 + (lane >> 4) * 4 + r;
        float fr = accR[mf][nf][r] * g + sr * (1.0f - g);
        float fi = accI[mf][nf][r] * g + si * (1.0f - g);
        size_t off = (size_t)t * 1024 + c;
        float pr = hp_re[off], pi = hp_im[off];
        Hrb[off] = f2bf(pr * odr - pi * odi + fr * ofr - fi * ofi);
      }
    }
}

// ---------------------------------------------------------------------------
// real NT GEMM, bf16: C = A@B^T.  KI = K/32.  3-buffer counted-vmcnt, BK=32.
// EPI=0 (mlp1): silu->bf16 direct.
// EPI=2 (u): softplus + FUSED fin: out0 = Hrb + nre*sqrt(bvar*u)*sqrt(0.5)
// ---------------------------------------------------------------------------
template<int KI, int EPI>
__global__ __launch_bounds__(TPB) void rgemm_nt_k(
    const u16* __restrict__ A, const u16* __restrict__ B,
    const float* __restrict__ bias,
    u16* __restrict__ C16, int nbxl, int total,
    const u16* __restrict__ HrbF, const float* __restrict__ nre,
    const float* __restrict__ bvarp, float* __restrict__ outp)
{
  __shared__ __align__(16) u16 lds[3 * 2 * PSZ];   // 24KB (ct needs 17.4KB)
  const int K = KI * 32;
  int tid = threadIdx.x;
  int flat = swz8(blockIdx.x, total);
  int bm = (flat >> nbxl) * 64;
  int bn = (flat & ((1 << nbxl) - 1)) * 64;
  const int N = 64 << nbxl;
  int lane = tid & 63;
  int wr = (tid >> 7) & 1, wc = (tid >> 6) & 1;
  int lr_ = ((tid & 63) >> 2) + ((tid >> 6) << 4);
  int ks_ = (((tid & 3) ^ ((tid >> 3) & 3)) << 3);
  u16* Lw_ = lds + ((tid >> 6) << 9);

  f32x4 acc[2][2] = {};

#define RG_STAGE(buf, k0)                                                    \
  { u16* Lb = Lw_ + (buf) * (2 * PSZ);                                       \
    gload16(A + (size_t)(bm + lr_) * K + (k0) + ks_, Lb + 0 * PSZ);          \
    gload16(B + (size_t)(bn + lr_) * K + (k0) + ks_, Lb + 1 * PSZ); }
#define RG_COMPUTE(buf)                                                      \
  { const u16* L = lds + (buf) * (2 * PSZ);                                  \
    int rA = wr * 32 + (lane & 15);                                          \
    int rB = wc * 32 + (lane & 15);                                          \
    int kq = lane >> 4;                                                      \
    bf8v a[2], b[2];                                                         \
    a[0] = fragld(L + 0 * PSZ, rA, kq);  a[1] = fragld(L + 0 * PSZ, rA + 16, kq); \
    b[0] = fragld(L + 1 * PSZ, rB, kq);  b[1] = fragld(L + 1 * PSZ, rB + 16, kq); \
    _Pragma("unroll")                                                        \
    for (int mf = 0; mf < 2; ++mf)                                           \
      _Pragma("unroll")                                                      \
      for (int nf = 0; nf < 2; ++nf)                                         \
        acc[mf][nf] = __builtin_amdgcn_mfma_f32_16x16x32_bf16(a[mf], b[nf], acc[mf][nf], 0, 0, 0); }

  RG_STAGE(0, 0);
  RG_STAGE(1, 32);
  #pragma unroll 1
  for (int t = 0; t < KI; ++t) {
    int bufc = t % 3;
    if (t + 2 < KI) { RG_STAGE((t + 2) % 3, (t + 2) * 32); }
    if (t + 2 < KI)      { WAITV(4); }
    else if (t + 1 < KI) { WAITV(2); }
    else                 { WAITV(0); }
    __builtin_amdgcn_sched_barrier(0);
    __builtin_amdgcn_s_barrier();
    __builtin_amdgcn_s_setprio(1);
    RG_COMPUTE(bufc)
    __builtin_amdgcn_s_setprio(0);
    __builtin_amdgcn_sched_barrier(0);
    __builtin_amdgcn_s_barrier();
  }

  if constexpr (EPI == 0) {
    #pragma unroll
    for (int mf = 0; mf < 2; ++mf)
      #pragma unroll
      for (int nf = 0; nf < 2; ++nf) {
        int c = bn + wc * 32 + nf * 16 + (lane & 15);
        #pragma unroll
        for (int r = 0; r < 4; ++r) {
          int t = bm + wr * 32 + mf * 16 + (lane >> 4) * 4 + r;
          float v = acc[mf][nf][r] + bias[c];
          v = v * sigmoidf_(v);                       // silu (fast exp)
          C16[(size_t)t * N + c] = f2bf(v);
        }
      }
  } else {
    // acc -> LDS f32 tile, then row-contiguous softplus + fused fin -> f32 out
    float* ct = (float*)lds;
    __syncthreads();
    #pragma unroll
    for (int mf = 0; mf < 2; ++mf)
      #pragma unroll
      for (int nf = 0; nf < 2; ++nf) {
        int rbase = wr * 32 + mf * 16 + (lane >> 4) * 4;
        int cc = wc * 32 + nf * 16 + (lane & 15);
        #pragma unroll
        for (int r = 0; r < 4; ++r)
          ct[(rbase + r) * CSTR + cc] = acc[mf][nf][r];
      }
    __syncthreads();
    int w = tid >> 6, l = tid & 63;
    int lcol = (l & 15) * 4;
    const float s2 = 0.7071067811865476f;
    #pragma unroll
    for (int p = 0; p < 4; ++p) {
      int lrow = w * 16 + p * 4 + (l >> 4);
      int t = bm + lrow;
      int c = bn + lcol;
      float4 v4 = *(float4*)&ct[lrow * CSTR + lcol];
      float4 bi4 = *(const float4*)(bias + c);
      float u0 = spf_(v4.x + bi4.x);
      float u1 = spf_(v4.y + bi4.y);
      float u2 = spf_(v4.z + bi4.z);
      float u3 = spf_(v4.w + bi4.w);
      size_t off = (size_t)t * 1024 + c;
      uint2 hb2 = *(const uint2*)(HrbF + off);
      float4 nr4 = *(const float4*)(nre + off);
      float4 bv4 = *(const float4*)(bvarp + c);
      float4 o;
      o.x = bf2f((u16)(hb2.x & 0xFFFF)) + nr4.x * sqrtf(bv4.x * u0) * s2;
      o.y = bf2f((u16)(hb2.x >> 16))    + nr4.y * sqrtf(bv4.y * u1) * s2;
      o.z = bf2f((u16)(hb2.y & 0xFFFF)) + nr4.z * sqrtf(bv4.z * u2) * s2;
      o.w = bf2f((u16)(hb2.y >> 16))    + nr4.w * sqrtf(bv4.w * u3) * s2;
      *(float4*)(outp + off) = o;
    }
  }
}

// ---------------------------------------------------------------------------
extern "C" void kernel_launch(void* const* d_in, const int* in_sizes, int n_in,
                              void* d_out, int out_size, void* d_ws, size_t ws_size,
                              hipStream_t stream) {
  (void)in_sizes; (void)n_in; (void)out_size;

  const float* x_input    = (const float*)d_in[0];
  const float* h_prev_re  = (const float*)d_in[1];
  const float* h_prev_im  = (const float*)d_in[2];
  const float* xg_re      = (const float*)d_in[3];
  const float* xg_im      = (const float*)d_in[4];
  const float* flux_re    = (const float*)d_in[5];
  const float* flux_im    = (const float*)d_in[6];
  const float* dt         = (const float*)d_in[7];
  const float* v_raw_re   = (const float*)d_in[10];
  const float* v_raw_im   = (const float*)d_in[11];
  const float* log_sigma  = (const float*)d_in[12];
  const float* dft_weight = (const float*)d_in[13];
  const float* decay_re   = (const float*)d_in[14];
  const float* decay_im   = (const float*)d_in[15];
  const float* Wi_in      = (const float*)d_in[16];
  const float* bi         = (const float*)d_in[17];
  const float* Wo         = (const float*)d_in[18];
  const float* bo         = (const float*)d_in[19];
  const float* Wg         = (const float*)d_in[20];
  const float* bg         = (const float*)d_in[21];
  const float* ld         = (const float*)d_in[22];
  const float* lf         = (const float*)d_in[23];
  const float* law_re     = (const float*)d_in[24];
  const float* law_im     = (const float*)d_in[25];
  const float* base_noise = (const float*)d_in[26];
  const float* Wu1        = (const float*)d_in[27];
  const float* bu1        = (const float*)d_in[28];
  const float* Wu2        = (const float*)d_in[29];
  const float* bu2        = (const float*)d_in[30];
  const float* noise_re   = (const float*)d_in[31];

  // --- workspace: 16 bf16-sized planes (2MB each) = 32MB --------------------
  const size_t PL16 = 1024ull * 1024ull;        // u16 per plane
  if (ws_size < 16 * PL16 * 2) return;          // too small -> zeros (diagnostic)

  u16* P = (u16*)d_ws;
  // liveness plan (d1..d7 = dispatch order):
  // P0,P1 : Ar,Ai (d1-d2) -> PpO+PpG in P0 (d4-d5)
  // P2,P3 : Nr,Ni (d1-d3) -> Mtr,Mti (d4-d5)
  // P4,P5 : A2 (d2-d3)    -> Hrb P4..P7 (d5-d7)
  // P6,P7 : A4 (d3-d4)    -> Hrb upper
  // P8,P9 : T1 (d3-d4)
  // P10-13: Xb (d2-d5)
  // P14   : PpI (d2-d3)   -> mlp1b (d6-d7)
  // P15   : Wu1b,Wu2b (d2-d7) + sm f32 region
  u16* Ar  = P + 0 * PL16;   u16* Ai  = P + 1 * PL16;
  u16* Nr  = P + 2 * PL16;   u16* Ni  = P + 3 * PL16;
  u16* A2r = P + 4 * PL16;   u16* A2i = P + 5 * PL16;
  u16* A4r = P + 6 * PL16;   u16* A4i = P + 7 * PL16;
  u16* T1r = P + 8 * PL16;   u16* T1i = P + 9 * PL16;
  u16* Mtr = P + 2 * PL16;   u16* Mti = P + 3 * PL16;
  u16* Xb  = P + 10 * PL16;            // P10..P13
  u16* Hrb = P + 4 * PL16;             // P4..P7
  float* PpO = (float*)(P + 0 * PL16); // 1MB
  float* PpG = PpO + 262144;           // 0.5MB (both inside P0)
  float* PpI = (float*)(P + 14 * PL16);// 1MB of P14
  u16* mlp1b = P + 14 * PL16;          // d6+
  u16* Wu1b  = P + 15 * PL16;          // 262144 u16
  u16* Wu2b  = Wu1b + 262144;
  float* sm  = (float*)(P + 15 * PL16 + 524288);
  float* FNr  = sm;                     // 16x1024
  float* FNi  = FNr + 16384;
  float* od_re = FNi + 16384;
  float* od_im = od_re + 1024;
  float* of_re = od_im + 1024;
  float* of_im = of_re + 1024;
  float* bvar  = of_im + 1024;

  float* out0f = (float*)d_out;                       // 4096x1024 f32 (real)
  float* out1f = out0f + (size_t)4096 * 1024;         // 16x1024 f32 (real)

  // d1: A/N build
  build_a_k<<<4096, TPB, 0, stream>>>(v_raw_re, v_raw_im, Ar, Ai, Nr, Ni);
  // d2: A2 gemm (512 x 64x32 tiles) + converts + prep + Wi gemm
  d2_k<<<3076, TPB, 0, stream>>>(Ar, Ai, A2r, A2i,
                                 x_input, Wu1, Wu2,
                                 ld, lf, law_re, law_im, dt, base_noise,
                                 Xb, Wu1b, Wu2b,
                                 od_re, od_im, of_re, of_im, bvar,
                                 xg_re, xg_im, Wi_in, PpI);
  // d3: pair (A4, T1) + fused Wi-reduce+flux
  d3_k<<<576, TPB, 0, stream>>>(A2r, A2i, Nr, Ni, A4r, A4i, T1r, T1i,
                                PpI, bi, flux_re, flux_im, decay_re, decay_im,
                                FNr, FNi, out1f);
  // d4: vmt (Mt build) + Wo/Wg gemm filler
  d4_k<<<896, TPB, 0, stream>>>(T1r, T1i, A4r, A4i, log_sigma, dft_weight,
                                Mtr, Mti,
                                FNr, FNi, Wo, Wg, PpO, PpG);
  // d5: x_tilde @ M + h_next epilogue (fused Wo/Wg reduce in-block)
  xmh_nt_k<<<512, TPB, 0, stream>>>(Xb, Mtr, Mti, PpO, PpG, bo, bg,
                                    od_re, od_im, of_re, of_im,
                                    h_prev_re, h_prev_im, Hrb);
  // d6: u-MLP layer 1 ; d7: u-MLP layer 2 + fused fin -> out0
  rgemm_nt_k<32, 0><<<256, TPB, 0, stream>>>(Hrb, Wu1b, bu1, mlp1b, 2, 256,
                                             nullptr, nullptr, nullptr, nullptr);
  rgemm_nt_k<8, 2><<<1024, TPB, 0, stream>>>(mlp1b, Wu2b, bu2, nullptr, 4, 1024,
                                             Hrb, noise_re, bvar, out0f);
}